// Round 3
// baseline (594.628 us; speedup 1.0000x reference)
//
#include <hip/hip_runtime.h>
#include <stdint.h>

typedef __bf16 bf16;
typedef __bf16 bf16x8 __attribute__((ext_vector_type(8)));
typedef __bf16 bf16x4v __attribute__((ext_vector_type(4)));
typedef float f32x4 __attribute__((ext_vector_type(4)));

#define L_SEQ 2048
#define H_DIM 2048
#define KV_DIM 512
#define QKV_LD 3072
#define INTER_DIM 8192

__device__ __forceinline__ void load_lds16(const void* g, void* l) {
  __builtin_amdgcn_global_load_lds(
      (const __attribute__((address_space(1))) void*)g,
      (__attribute__((address_space(3))) void*)l, 16, 0, 0);
}

// ---------------- fused fp32 -> bf16 convert of all 7 weights -------------
__global__ __launch_bounds__(256)
void cvt_all(const float* __restrict__ q, const float* __restrict__ k,
             const float* __restrict__ v, const float* __restrict__ o,
             const float* __restrict__ g, const float* __restrict__ u,
             const float* __restrict__ dn, bf16* __restrict__ WB) {
  const int b = blockIdx.x;
  const float* s;
  size_t doff;
  int lb;
  if (b < 2048)       { s = q;  doff = 0;        lb = b; }
  else if (b < 2560)  { s = k;  doff = 4194304;  lb = b - 2048; }
  else if (b < 3072)  { s = v;  doff = 5242880;  lb = b - 2560; }
  else if (b < 5120)  { s = o;  doff = 6291456;  lb = b - 3072; }
  else if (b < 13312) { s = g;  doff = 10485760; lb = b - 5120; }
  else if (b < 21504) { s = u;  doff = 27262976; lb = b - 13312; }
  else                { s = dn; doff = 44040192; lb = b - 21504; }
  const size_t i = (size_t)lb * 2048 + threadIdx.x * 8;
  float4 a = *(const float4*)(s + i);
  float4 c = *(const float4*)(s + i + 4);
  bf16x8 ov;
  ov[0] = (bf16)a.x; ov[1] = (bf16)a.y; ov[2] = (bf16)a.z; ov[3] = (bf16)a.w;
  ov[4] = (bf16)c.x; ov[5] = (bf16)c.y; ov[6] = (bf16)c.z; ov[7] = (bf16)c.w;
  *(bf16x8*)(WB + doff + i) = ov;
}

// ---------------- RMSNorm: fp32 in -> bf16 out ----------------
__global__ __launch_bounds__(256)
void rmsnorm_bf16(const float* __restrict__ x, const float* __restrict__ w,
                  bf16* __restrict__ out) {
  const int row = blockIdx.x;
  const int t = threadIdx.x;
  const float* xr = x + (size_t)row * H_DIM + t * 8;
  float4 a = *(const float4*)xr;
  float4 b = *(const float4*)(xr + 4);
  float ss = a.x * a.x + a.y * a.y + a.z * a.z + a.w * a.w +
             b.x * b.x + b.y * b.y + b.z * b.z + b.w * b.w;
#pragma unroll
  for (int off = 1; off < 64; off <<= 1) ss += __shfl_xor(ss, off, 64);
  __shared__ float red[4];
  if ((t & 63) == 0) red[t >> 6] = ss;
  __syncthreads();
  ss = red[0] + red[1] + red[2] + red[3];
  const float rs = rsqrtf(ss * (1.0f / H_DIM) + 1e-6f);
  float4 w1 = *(const float4*)(w + t * 8);
  float4 w2 = *(const float4*)(w + t * 8 + 4);
  bf16x8 o;
  o[0] = (bf16)(a.x * rs * w1.x);
  o[1] = (bf16)(a.y * rs * w1.y);
  o[2] = (bf16)(a.z * rs * w1.z);
  o[3] = (bf16)(a.w * rs * w1.w);
  o[4] = (bf16)(b.x * rs * w2.x);
  o[5] = (bf16)(b.y * rs * w2.y);
  o[6] = (bf16)(b.z * rs * w2.z);
  o[7] = (bf16)(b.w * rs * w2.w);
  *(bf16x8*)(out + (size_t)row * H_DIM + t * 8) = o;
}

// -------- fused: hidden = p0+p1+res ; normed = rmsnorm(hidden) --------
__global__ __launch_bounds__(256)
void add_rmsnorm(const float* __restrict__ p0, const float* __restrict__ p1,
                 const float* __restrict__ res, const float* __restrict__ w,
                 float* __restrict__ hidden, bf16* __restrict__ normed) {
  const int row = blockIdx.x;
  const int t = threadIdx.x;
  const size_t base = (size_t)row * H_DIM + t * 8;
  float4 a0 = *(const float4*)(p0 + base);
  float4 a1 = *(const float4*)(p0 + base + 4);
  float4 b0 = *(const float4*)(p1 + base);
  float4 b1 = *(const float4*)(p1 + base + 4);
  float4 c0 = *(const float4*)(res + base);
  float4 c1 = *(const float4*)(res + base + 4);
  float4 h0, h1;
  h0.x = a0.x + b0.x + c0.x; h0.y = a0.y + b0.y + c0.y;
  h0.z = a0.z + b0.z + c0.z; h0.w = a0.w + b0.w + c0.w;
  h1.x = a1.x + b1.x + c1.x; h1.y = a1.y + b1.y + c1.y;
  h1.z = a1.z + b1.z + c1.z; h1.w = a1.w + b1.w + c1.w;
  *(float4*)(hidden + base) = h0;
  *(float4*)(hidden + base + 4) = h1;
  float ss = h0.x * h0.x + h0.y * h0.y + h0.z * h0.z + h0.w * h0.w +
             h1.x * h1.x + h1.y * h1.y + h1.z * h1.z + h1.w * h1.w;
#pragma unroll
  for (int off = 1; off < 64; off <<= 1) ss += __shfl_xor(ss, off, 64);
  __shared__ float red[4];
  if ((t & 63) == 0) red[t >> 6] = ss;
  __syncthreads();
  ss = red[0] + red[1] + red[2] + red[3];
  const float rs = rsqrtf(ss * (1.0f / H_DIM) + 1e-6f);
  float4 w1 = *(const float4*)(w + t * 8);
  float4 w2 = *(const float4*)(w + t * 8 + 4);
  bf16x8 o;
  o[0] = (bf16)(h0.x * rs * w1.x);
  o[1] = (bf16)(h0.y * rs * w1.y);
  o[2] = (bf16)(h0.z * rs * w1.z);
  o[3] = (bf16)(h0.w * rs * w1.w);
  o[4] = (bf16)(h1.x * rs * w2.x);
  o[5] = (bf16)(h1.y * rs * w2.y);
  o[6] = (bf16)(h1.z * rs * w2.z);
  o[7] = (bf16)(h1.w * rs * w2.w);
  *(bf16x8*)(normed + (size_t)row * H_DIM + t * 8) = o;
}

// ---------------- out = p0+p1+p2+p3 + res (float4) ----------------
__global__ __launch_bounds__(256)
void reduce_add4(const float* __restrict__ p, size_t zs,
                 const float* __restrict__ res, float* __restrict__ out) {
  const size_t i = ((size_t)blockIdx.x * 256 + threadIdx.x) * 4;
  float4 a = *(const float4*)(p + i);
  float4 b = *(const float4*)(p + zs + i);
  float4 c = *(const float4*)(p + 2 * zs + i);
  float4 d = *(const float4*)(p + 3 * zs + i);
  float4 r = *(const float4*)(res + i);
  float4 o;
  o.x = a.x + b.x + c.x + d.x + r.x;
  o.y = a.y + b.y + c.y + d.y + r.y;
  o.z = a.z + b.z + c.z + d.z + r.z;
  o.w = a.w + b.w + c.w + d.w + r.w;
  *(float4*)(out + i) = o;
}

// ------- qkv combine: sum 2 fp32 partials -> bf16 qkv + fp32 K/V out ------
__global__ __launch_bounds__(256)
void qkv_combine(const float* __restrict__ p, size_t zs,
                 bf16* __restrict__ qkv, float* __restrict__ outk,
                 float* __restrict__ outv) {
  const size_t i = ((size_t)blockIdx.x * 256 + threadIdx.x) * 4;
  float4 a = *(const float4*)(p + i);
  float4 b = *(const float4*)(p + zs + i);
  float4 s;
  s.x = a.x + b.x; s.y = a.y + b.y; s.z = a.z + b.z; s.w = a.w + b.w;
  bf16x4v o;
  o[0] = (bf16)s.x; o[1] = (bf16)s.y; o[2] = (bf16)s.z; o[3] = (bf16)s.w;
  *(bf16x4v*)(qkv + i) = o;
  const int col = (int)(i % QKV_LD);
  const size_t row = i / QKV_LD;
  if (col >= 2560)      *(float4*)(outv + row * KV_DIM + (col - 2560)) = s;
  else if (col >= 2048) *(float4*)(outk + row * KV_DIM + (col - 2048)) = s;
}

// ============ 256x256 BK=32 3-stage free-running GEMM engine ==============
// 512 thr = 8 waves (2M x 4N); per-wave out 128x64 (acc 32 f32x4).
// LDS 96 KiB: 3 buffers x {A0,A1,B0,B1} 8KB chunks (128 rows x 64 B).
// ONE barrier + ONE counted vmcnt(4) per K-tile; the tile body (4 staging
// gload_lds + 12 ds_read_b128 + 32 MFMA) is left entirely to the compiler
// scheduler so ds_reads interleave with MFMAs (fine-grained lgkmcnt) and
// waves drift within the tile, overlapping each other's LDS/matrix use.
// Staging runs 2 tiles ahead (tile t issues t+2 into buf (t+2)%3), so
// vmcnt(4) confirms tile t's 4 chunks while t+1's 4 stay in flight.
// Swizzle (64 B rows, 4 slots): LDS(row r, slot s) = global k-slot
// s ^ ((r>>1)&3). Bank-quad = (4*(r&1) + (s ^ ((r>>1)&3))) & 7 -> exactly
// 8 lanes/quad for both the staged write order and the b128 frag reads.

#define WAIT_VM(n) asm volatile("s_waitcnt vmcnt(" #n ")" ::: "memory")

#define ISSUE_TILE(ko, base)                          \
  load_lds16(pa0 + (ko), (base) + dln);               \
  load_lds16(pa1 + (ko), (base) + 8192 + dln);        \
  load_lds16(pb0 + (ko), (base) + 16384 + dln);       \
  load_lds16(pb1 + (ko), (base) + 24576 + dln);

#define MFMA_Q(mh, nh, bfr)                                                  \
  _Pragma("unroll") for (int mi = 0; mi < 4; ++mi)                           \
      _Pragma("unroll") for (int ni = 0; ni < 2; ++ni)                       \
          acc[mh][nh][mi][ni] = __builtin_amdgcn_mfma_f32_16x16x32_bf16(     \
              af[mi], bfr[ni], acc[mh][nh][mi][ni], 0, 0, 0);

// ---- split-K B^T GEMM: C[M,N] = A[M,K] @ B[N,K]^T, fp32 partials ----
__global__ __launch_bounds__(512, 2)
void gemm32_bt(const bf16* __restrict__ A, int lda,
               const bf16* __restrict__ B, int ldb, int kpb,
               float* __restrict__ outf, int ldof, size_t zstride) {
  __shared__ __align__(16) char smb[98304];  // 3 x 32 KB
  const int t = threadIdx.x;
  const int lane = t & 63;
  const int l15 = lane & 15, l4 = lane >> 4;
  const int wid = t >> 6;
  const int wr = wid >> 2, wc = wid & 3;

  // block mapping: partition N across XCDs when gn % 8 == 0
  const int gn = gridDim.x;
  const int bid = blockIdx.y * gn + blockIdx.x;
  int mb, nb;
  if ((gn & 7) == 0) {
    const int j = bid & 7, local = bid >> 3, npx = gn >> 3;
    nb = j * npx + local % npx;
    mb = local / npx;
  } else {
    nb = bid % gn;
    mb = bid / gn;
  }
  const int m0 = mb * 256, n0 = nb * 256;
  const int kbeg = blockIdx.z * kpb;
  const int NT = kpb >> 5;

  // frag byte offsets within an 8 KB chunk (row*64 + swizzled 16B slot)
  int aoff[4], boff[2];
#pragma unroll
  for (int mi = 0; mi < 4; ++mi) {
    const int rA = wr * 64 + mi * 16 + l15;
    aoff[mi] = rA * 64 + ((l4 ^ ((rA >> 1) & 3)) << 4);
  }
#pragma unroll
  for (int ni = 0; ni < 2; ++ni) {
    const int rB = wc * 32 + ni * 16 + l15;
    boff[ni] = rB * 64 + ((l4 ^ ((rB >> 1) & 3)) << 4);
  }

  // staging: thread t -> chunk row r=t>>2, slot s=t&3; source pre-swizzled
  const int r = t >> 2;
  const int gsw = (((t & 3) ^ ((r >> 1) & 3)) << 3);  // element offset
  const bf16* pa0 = A + (size_t)(m0 + r) * lda + kbeg + gsw;
  const bf16* pa1 = A + (size_t)(m0 + 128 + r) * lda + kbeg + gsw;
  const bf16* pb0 = B + (size_t)(n0 + r) * ldb + kbeg + gsw;
  const bf16* pb1 = B + (size_t)(n0 + 128 + r) * ldb + kbeg + gsw;
  const int dln = t * 16;

  // prologue: tile 0 -> buf0, tile 1 -> buf1
  ISSUE_TILE(0, smb);
  if (NT > 1) { ISSUE_TILE(32, smb + 32768); }

  const f32x4 zero = {0.f, 0.f, 0.f, 0.f};
  f32x4 acc[2][2][4][2];
#pragma unroll
  for (int mh = 0; mh < 2; ++mh)
#pragma unroll
    for (int nh = 0; nh < 2; ++nh)
#pragma unroll
      for (int mi = 0; mi < 4; ++mi)
#pragma unroll
        for (int ni = 0; ni < 2; ++ni) acc[mh][nh][mi][ni] = zero;

  int br = 0, bw = 2;  // read buf, stage-target buf (= (tt+2)%3)
#pragma unroll 1
  for (int tt = 0; tt < NT; ++tt) {
    if (tt + 1 < NT) { WAIT_VM(4); } else { WAIT_VM(0); }
    __builtin_amdgcn_s_barrier();
    if (tt + 2 < NT) {
      char* dst = smb + bw * 32768;
      const int ko = (tt + 2) * 32;
      ISSUE_TILE(ko, dst);
    }
    const char* bb = smb + br * 32768;
    const char* cA0 = bb;
    const char* cA1 = bb + 8192;
    const char* cB0 = bb + 16384;
    const char* cB1 = bb + 24576;

    bf16x8 af[4], b0f[2], b1f[2];
#pragma unroll
    for (int mi = 0; mi < 4; ++mi)
      af[mi] = *(const bf16x8*)(cA0 + aoff[mi]);
#pragma unroll
    for (int ni = 0; ni < 2; ++ni) b0f[ni] = *(const bf16x8*)(cB0 + boff[ni]);
#pragma unroll
    for (int ni = 0; ni < 2; ++ni) b1f[ni] = *(const bf16x8*)(cB1 + boff[ni]);
    MFMA_Q(0, 0, b0f);
    MFMA_Q(0, 1, b1f);
#pragma unroll
    for (int mi = 0; mi < 4; ++mi)
      af[mi] = *(const bf16x8*)(cA1 + aoff[mi]);
    MFMA_Q(1, 0, b0f);
    MFMA_Q(1, 1, b1f);

    br = (br == 2) ? 0 : br + 1;
    bw = (bw == 2) ? 0 : bw + 1;
  }

  // C/D layout: col = lane&15, row = (lane>>4)*4 + reg
  float* outz = outf + zstride * blockIdx.z;
#pragma unroll
  for (int mh = 0; mh < 2; ++mh)
#pragma unroll
    for (int nh = 0; nh < 2; ++nh)
#pragma unroll
      for (int mi = 0; mi < 4; ++mi)
#pragma unroll
        for (int ni = 0; ni < 2; ++ni) {
          const int row0 = m0 + mh * 128 + wr * 64 + mi * 16 + l4 * 4;
          const int col = n0 + nh * 128 + wc * 32 + ni * 16 + l15;
#pragma unroll
          for (int rr2 = 0; rr2 < 4; ++rr2)
            outz[(size_t)(row0 + rr2) * ldof + col] = acc[mh][nh][mi][ni][rr2];
        }
}

// ---- fused GLU: B chunk0 = gate rows, chunk1 = up rows (same 128 cols);
// acc[mh][0]=gate, acc[mh][1]=up -> in-register silu(g)*u epilogue.
__global__ __launch_bounds__(512, 2)
void gemm32_glu(const bf16* __restrict__ A, const bf16* __restrict__ Bg,
                const bf16* __restrict__ Bu, bf16* __restrict__ out) {
  __shared__ __align__(16) char smb[98304];
  const int t = threadIdx.x;
  const int lane = t & 63;
  const int l15 = lane & 15, l4 = lane >> 4;
  const int wid = t >> 6;
  const int wr = wid >> 2, wc = wid & 3;

  const int gn = gridDim.x;  // 64
  const int bid = blockIdx.y * gn + blockIdx.x;
  const int j = bid & 7, local = bid >> 3, npx = gn >> 3;
  const int nb = j * npx + local % npx;
  const int mb = local / npx;
  const int m0 = mb * 256, n0 = nb * 128;
  const int NT = H_DIM / 32;  // 64

  int aoff[4], boff[2];
#pragma unroll
  for (int mi = 0; mi < 4; ++mi) {
    const int rA = wr * 64 + mi * 16 + l15;
    aoff[mi] = rA * 64 + ((l4 ^ ((rA >> 1) & 3)) << 4);
  }
#pragma unroll
  for (int ni = 0; ni < 2; ++ni) {
    const int rB = wc * 32 + ni * 16 + l15;
    boff[ni] = rB * 64 + ((l4 ^ ((rB >> 1) & 3)) << 4);
  }

  const int r = t >> 2;
  const int gsw = (((t & 3) ^ ((r >> 1) & 3)) << 3);
  const bf16* pa0 = A + (size_t)(m0 + r) * H_DIM + gsw;
  const bf16* pa1 = A + (size_t)(m0 + 128 + r) * H_DIM + gsw;
  const bf16* pb0 = Bg + (size_t)(n0 + r) * H_DIM + gsw;
  const bf16* pb1 = Bu + (size_t)(n0 + r) * H_DIM + gsw;
  const int dln = t * 16;

  ISSUE_TILE(0, smb);
  ISSUE_TILE(32, smb + 32768);

  const f32x4 zero = {0.f, 0.f, 0.f, 0.f};
  f32x4 acc[2][2][4][2];
#pragma unroll
  for (int mh = 0; mh < 2; ++mh)
#pragma unroll
    for (int nh = 0; nh < 2; ++nh)
#pragma unroll
      for (int mi = 0; mi < 4; ++mi)
#pragma unroll
        for (int ni = 0; ni < 2; ++ni) acc[mh][nh][mi][ni] = zero;

  int br = 0, bw = 2;
#pragma unroll 1
  for (int tt = 0; tt < NT; ++tt) {
    if (tt + 1 < NT) { WAIT_VM(4); } else { WAIT_VM(0); }
    __builtin_amdgcn_s_barrier();
    if (tt + 2 < NT) {
      char* dst = smb + bw * 32768;
      const int ko = (tt + 2) * 32;
      ISSUE_TILE(ko, dst);
    }
    const char* bb = smb + br * 32768;
    const char* cA0 = bb;
    const char* cA1 = bb + 8192;
    const char* cB0 = bb + 16384;
    const char* cB1 = bb + 24576;

    bf16x8 af[4], b0f[2], b1f[2];
#pragma unroll
    for (int mi = 0; mi < 4; ++mi)
      af[mi] = *(const bf16x8*)(cA0 + aoff[mi]);
#pragma unroll
    for (int ni = 0; ni < 2; ++ni) b0f[ni] = *(const bf16x8*)(cB0 + boff[ni]);
#pragma unroll
    for (int ni = 0; ni < 2; ++ni) b1f[ni] = *(const bf16x8*)(cB1 + boff[ni]);
    MFMA_Q(0, 0, b0f);
    MFMA_Q(0, 1, b1f);
#pragma unroll
    for (int mi = 0; mi < 4; ++mi)
      af[mi] = *(const bf16x8*)(cA1 + aoff[mi]);
    MFMA_Q(1, 0, b0f);
    MFMA_Q(1, 1, b1f);

    br = (br == 2) ? 0 : br + 1;
    bw = (bw == 2) ? 0 : bw + 1;
  }

  // epilogue: in-register GLU fusion (gate = nh0, up = nh1, same cols)
#pragma unroll
  for (int mh = 0; mh < 2; ++mh)
#pragma unroll
    for (int mi = 0; mi < 4; ++mi)
#pragma unroll
      for (int ni = 0; ni < 2; ++ni) {
        const int row0 = m0 + mh * 128 + wr * 64 + mi * 16 + l4 * 4;
        const int col = n0 + wc * 32 + ni * 16 + l15;
#pragma unroll
        for (int rr2 = 0; rr2 < 4; ++rr2) {
          const float g = acc[mh][0][mi][ni][rr2];
          const float u = acc[mh][1][mi][ni][rr2];
          const float sg = g / (1.f + __expf(-g));
          out[(size_t)(row0 + rr2) * INTER_DIM + col] = (bf16)(sg * u);
        }
      }
}

// ---------------- GEMM: C[M,N] = A[M,K](bf16) @ B[N,K](bf16)^T -------------
// (m97-structure 128x128 kernel, kept for the O projection)
__global__ __launch_bounds__(256, 3)
void gemm_bt(const bf16* __restrict__ A, int lda,
             const bf16* __restrict__ B, int ldb, int kpb,
             float* __restrict__ outf, int ldof, size_t zstride) {
  __shared__ bf16 sA[2 * 128 * 32];
  __shared__ bf16 sB[2 * 128 * 32];
  const int t = threadIdx.x;
  const int lane = t & 63;
  const int l15 = lane & 15, l4 = lane >> 4;
  const int wm = ((t >> 6) >> 1) * 64;
  const int wn = ((t >> 6) & 1) * 64;
  const int m0 = blockIdx.y * 128;
  const int n0 = blockIdx.x * 128;
  const int kbeg = blockIdx.z * kpb;
  const int kend = kbeg + kpb;

  const f32x4 zero = {0.f, 0.f, 0.f, 0.f};
  f32x4 acc[4][4];
#pragma unroll
  for (int i = 0; i < 4; ++i)
#pragma unroll
    for (int j = 0; j < 4; ++j) acc[i][j] = zero;

  for (int k0 = kbeg; k0 < kend; k0 += 64) {
#pragma unroll
    for (int i = 0; i < 4; ++i) {
      const int flat = i * 4096 + t * 16;
      const int kc = flat >> 13;
      const int wb = flat & 8191;
      const int r = wb >> 6, ce = (wb & 63) >> 1;
      const int gc = k0 + kc * 32 + ce;
      load_lds16(A + (size_t)(m0 + r) * lda + gc, (char*)sA + flat);
      load_lds16(B + (size_t)(n0 + r) * ldb + gc, (char*)sB + flat);
    }
    __syncthreads();

#pragma unroll
    for (int kc = 0; kc < 2; ++kc) {
      bf16x8 af[4], bfr[4];
#pragma unroll
      for (int mi = 0; mi < 4; ++mi)
        af[mi] = *(const bf16x8*)(&sA[kc * 4096 + (wm + mi * 16 + l15) * 32 +
                                      l4 * 8]);
#pragma unroll
      for (int ni = 0; ni < 4; ++ni)
        bfr[ni] = *(const bf16x8*)(&sB[kc * 4096 + (wn + ni * 16 + l15) * 32 +
                                       l4 * 8]);
#pragma unroll
      for (int mi = 0; mi < 4; ++mi)
#pragma unroll
        for (int ni = 0; ni < 4; ++ni)
          acc[mi][ni] = __builtin_amdgcn_mfma_f32_16x16x32_bf16(
              af[mi], bfr[ni], acc[mi][ni], 0, 0, 0);
    }
    __syncthreads();
  }

#pragma unroll
  for (int mi = 0; mi < 4; ++mi) {
#pragma unroll
    for (int ni = 0; ni < 4; ++ni) {
      const int row0 = m0 + wm + mi * 16 + l4 * 4;
      const int col = n0 + wn + ni * 16 + l15;
#pragma unroll
      for (int r = 0; r < 4; ++r)
        outf[zstride * blockIdx.z + (size_t)(row0 + r) * ldof + col] =
            acc[mi][ni][r];
    }
  }
}

// ---------------- Flash attention, segment-causal ----------------
__global__ __launch_bounds__(256, 2)
void attn_fwd(const bf16* __restrict__ qkv, const int* __restrict__ cu,
              bf16* __restrict__ out) {
  const int h = blockIdx.y;
  const int q0 = blockIdx.x * 64;
  const int kvh = h >> 2;
  const int t = threadIdx.x;
  const int lane = t & 63;
  const int w = t >> 6;
  const int l15 = lane & 15, l4 = lane >> 4;

  __shared__ bf16 sK[64 * 136];
  __shared__ bf16 sVt[128 * 72];
  __shared__ bf16 sP[4][16 * 64];

  const int c1 = cu[1], c2 = cu[2];
  const int seg0 = (q0 >= c2) ? c2 : ((q0 >= c1) ? c1 : 0);

  const int qrow = q0 + w * 16 + l15;
  bf16x8 qf[4];
#pragma unroll
  for (int kc = 0; kc < 4; ++kc) {
    bf16x8 v = *(const bf16x8*)(qkv + (size_t)qrow * QKV_LD + h * 128 +
                                kc * 32 + l4 * 8);
#pragma unroll
    for (int j = 0; j < 8; ++j)
      v[j] = (bf16)((float)v[j] * 0.08838834764831845f);
    qf[kc] = v;
  }

  const f32x4 zero = {0.f, 0.f, 0.f, 0.f};
  f32x4 oacc[8];
#pragma unroll
  for (int i = 0; i < 8; ++i) oacc[i] = zero;
  float mi[4] = {-1e30f, -1e30f, -1e30f, -1e30f};
  float li[4] = {0.f, 0.f, 0.f, 0.f};

  for (int k0 = seg0; k0 <= q0; k0 += 64) {
#pragma unroll
    for (int it = 0; it < 4; ++it) {
      const int flat = it * 4096 + t * 16;
      const int r = flat >> 8, db = flat & 255;
      *(bf16x8*)((char*)sK + r * 272 + db) = *(const bf16x8*)(
          (const char*)(qkv + (size_t)(k0 + r) * QKV_LD + 2048 + kvh * 128) +
          db);
      const int chunk = it * 256 + t;
      const int vr = chunk & 63, dc = chunk >> 6;
      bf16x8 vv = *(const bf16x8*)(qkv + (size_t)(k0 + vr) * QKV_LD + 2560 +
                                   kvh * 128 + dc * 8);
#pragma unroll
      for (int j = 0; j < 8; ++j) sVt[(dc * 8 + j) * 72 + vr] = vv[j];
    }
    __syncthreads();

    f32x4 sacc[4];
#pragma unroll
    for (int kg = 0; kg < 4; ++kg) {
      f32x4 a = zero;
#pragma unroll
      for (int kc = 0; kc < 4; ++kc) {
        bf16x8 kf = *(const bf16x8*)((const char*)sK + (kg * 16 + l15) * 272 +
                                     kc * 64 + l4 * 16);
        a = __builtin_amdgcn_mfma_f32_16x16x32_bf16(qf[kc], kf, a, 0, 0, 0);
      }
      sacc[kg] = a;
    }

    if (k0 == q0) {
#pragma unroll
      for (int kg = 0; kg < 4; ++kg) {
        const int kk = kg * 16 + l15;
#pragma unroll
        for (int r = 0; r < 4; ++r) {
          const int qq = w * 16 + l4 * 4 + r;
          if (kk > qq) sacc[kg][r] = -1e30f;
        }
      }
    }

    float mx[4], al[4], rs[4];
#pragma unroll
    for (int r = 0; r < 4; ++r)
      mx[r] = fmaxf(fmaxf(sacc[0][r], sacc[1][r]),
                    fmaxf(sacc[2][r], sacc[3][r]));
#pragma unroll
    for (int off = 1; off < 16; off <<= 1)
#pragma unroll
      for (int r = 0; r < 4; ++r)
        mx[r] = fmaxf(mx[r], __shfl_xor(mx[r], off, 64));
#pragma unroll
    for (int r = 0; r < 4; ++r) {
      const float mn = fmaxf(mi[r], mx[r]);
      al[r] = __expf(mi[r] - mn);
      mi[r] = mn;
      rs[r] = 0.f;
    }
#pragma unroll
    for (int kg = 0; kg < 4; ++kg)
#pragma unroll
      for (int r = 0; r < 4; ++r) {
        const float p = __expf(sacc[kg][r] - mi[r]);
        sacc[kg][r] = p;
        rs[r] += p;
      }
#pragma unroll
    for (int off = 1; off < 16; off <<= 1)
#pragma unroll
      for (int r = 0; r < 4; ++r) rs[r] += __shfl_xor(rs[r], off, 64);
#pragma unroll
    for (int r = 0; r < 4; ++r) li[r] = li[r] * al[r] + rs[r];
#pragma unroll
    for (int dn = 0; dn < 8; ++dn)
#pragma unroll
      for (int r = 0; r < 4; ++r) oacc[dn][r] *= al[r];

#pragma unroll
    for (int kg = 0; kg < 4; ++kg)
#pragma unroll
      for (int r = 0; r < 4; ++r)
        sP[w][(l4 * 4 + r) * 64 + kg * 16 + l15] = (bf16)sacc[kg][r];

    bf16x8 pf[2];
#pragma unroll
    for (int kc2 = 0; kc2 < 2; ++kc2)
      pf[kc2] = *(const bf16x8*)(&sP[w][l15 * 64 + kc2 * 32 + l4 * 8]);
#pragma unroll
    for (int dn = 0; dn < 8; ++dn)
#pragma unroll
      for (int kc2 = 0; kc2 < 2; ++kc2) {
        bf16x8 vf = *(const bf16x8*)(&sVt[(dn * 16 + l15) * 72 + kc2 * 32 +
                                          l4 * 8]);
        oacc[dn] = __builtin_amdgcn_mfma_f32_16x16x32_bf16(pf[kc2], vf,
                                                           oacc[dn], 0, 0, 0);
      }
    __syncthreads();
  }

#pragma unroll
  for (int dn = 0; dn < 8; ++dn)
#pragma unroll
    for (int r = 0; r < 4; ++r) {
      const size_t m = (size_t)(q0 + w * 16 + l4 * 4 + r);
      out[m * H_DIM + h * 128 + dn * 16 + l15] = (bf16)(oacc[dn][r] / li[r]);
    }
}

// ---------------- Host launcher ----------------
extern "C" void kernel_launch(void* const* d_in, const int* in_sizes, int n_in,
                              void* d_out, int out_size, void* d_ws,
                              size_t ws_size, hipStream_t stream) {
  (void)in_sizes; (void)n_in; (void)out_size; (void)ws_size;
  const float* hs     = (const float*)d_in[0];
  const int*   cu     = (const int*)d_in[1];
  const float* ln1    = (const float*)d_in[2];
  const float* ln2    = (const float*)d_in[3];
  const float* q_w    = (const float*)d_in[4];
  const float* k_w    = (const float*)d_in[5];
  const float* v_w    = (const float*)d_in[6];
  const float* o_w    = (const float*)d_in[7];
  const float* gate_w = (const float*)d_in[8];
  const float* up_w   = (const float*)d_in[9];
  const float* down_w = (const float*)d_in[10];

  float* out_hidden = (float*)d_out;
  float* out_k = out_hidden + (size_t)L_SEQ * H_DIM;
  float* out_v = out_k + (size_t)L_SEQ * KV_DIM;

  char* ws = (char*)d_ws;
  bf16* WB = (bf16*)ws;
  const size_t wq_off = 0;
  const size_t wo_off = 6291456;
  const size_t wg_off = 10485760;
  const size_t wu_off = 27262976;
  const size_t wd_off = 44040192;

  bf16*  normed1 = (bf16*)(ws + ((size_t)116 << 20));
  bf16*  qkv     = (bf16*)(ws + ((size_t)124 << 20));
  bf16*  attnb   = (bf16*)(ws + ((size_t)136 << 20));
  bf16*  normed2 = (bf16*)(ws + ((size_t)144 << 20));
  bf16*  interb  = (bf16*)(ws + ((size_t)152 << 20));
  float* qpart   = (float*)(ws + ((size_t)136 << 20));
  float* opart   = (float*)(ws + ((size_t)152 << 20));
  float* dpart   = (float*)(ws);

  dim3 blk(256);

  // 0) convert all weights to bf16
  cvt_all<<<29696, blk, 0, stream>>>(q_w, k_w, v_w, o_w, gate_w, up_w, down_w,
                                     WB);

  // 1) normed1 = rmsnorm(hidden_states)
  rmsnorm_bf16<<<L_SEQ, blk, 0, stream>>>(hs, ln1, normed1);

  // 2) QKV projection (3-stage engine), split-K=2 -> partials; combine
  gemm32_bt<<<dim3(12, 8, 2), dim3(512), 0, stream>>>(
      normed1, H_DIM, WB + wq_off, H_DIM, 1024, qpart, QKV_LD,
      (size_t)L_SEQ * QKV_LD);
  qkv_combine<<<6144, blk, 0, stream>>>(qpart, (size_t)L_SEQ * QKV_LD, qkv,
                                        out_k, out_v);

  // 3) attention
  attn_fwd<<<dim3(32, 16), blk, 0, stream>>>(qkv, cu, attnb);

  // 4) O projection (m97 kernel), split-K=2 -> partials
  gemm_bt<<<dim3(16, 16, 2), blk, 0, stream>>>(
      attnb, H_DIM, WB + wo_off, H_DIM, 1024, opart, H_DIM,
      (size_t)L_SEQ * H_DIM);

  // 5) hidden = opart0+opart1+hs ; normed2 = rmsnorm(hidden)
  add_rmsnorm<<<L_SEQ, blk, 0, stream>>>(opart, opart + (size_t)L_SEQ * H_DIM,
                                         hs, ln2, out_hidden, normed2);

  // 6) inter = silu(normed2 @ gate^T) * (normed2 @ up^T)  (fused, 3-stage)
  gemm32_glu<<<dim3(64, 8), dim3(512), 0, stream>>>(normed2, WB + wg_off,
                                                    WB + wu_off, interb);

  // 7) down projection (3-stage engine), split-K=4 -> partials
  gemm32_bt<<<dim3(8, 8, 4), dim3(512), 0, stream>>>(
      interb, INTER_DIM, WB + wd_off, INTER_DIM, 2048, dpart, H_DIM,
      (size_t)L_SEQ * H_DIM);

  // 8) out = sum(dpart[0..3]) + hidden
  reduce_add4<<<4096, blk, 0, stream>>>(dpart, (size_t)L_SEQ * H_DIM,
                                        out_hidden, out_hidden);
}